// Round 4
// baseline (405.098 us; speedup 1.0000x reference)
//
#include <hip/hip_runtime.h>

// Native clang vector type — accepted by __builtin_nontemporal_load
typedef float vf2 __attribute__((ext_vector_type(2)));

// Workspace float offsets
#define WS_F     0      // f[128]
#define WS_FEAT0 128    // feat0[450]
#define WS_H1    640    // h1[450]
#define WS_FEAT  1152   // feat[450]
#define WS_H2    1664   // h2[450]
#define WS_CNT   2176   // int barrier counter (zeroed via hipMemsetAsync)

// Grid barrier: release-RMW arrival + acquire-load poll, both agent scope.
// 128 blocks, all co-resident (256 CUs). Monotonic counter, no reset per phase.
__device__ __forceinline__ void gbar(int* cnt, int target) {
  __syncthreads();
  if (threadIdx.x == 0) {
    __hip_atomic_fetch_add(cnt, 1, __ATOMIC_RELEASE, __HIP_MEMORY_SCOPE_AGENT);
    while (__hip_atomic_load(cnt, __ATOMIC_ACQUIRE, __HIP_MEMORY_SCOPE_AGENT) < target) {
      __builtin_amdgcn_s_sleep(2);
    }
  }
  __syncthreads();
}

// 450x450 matvec phase: vout = [relu](W@vin + b). Wave per row.
__device__ __forceinline__ void phase_mv450(
    const float* __restrict__ W, const float* __restrict__ b,
    const float* __restrict__ vin, float* __restrict__ vout,
    int relu, float* sv) {
  const int tid = threadIdx.x;
  if (tid < 450) sv[tid] = vin[tid];
  if (tid + 256 < 450) sv[tid + 256] = vin[tid + 256];
  __syncthreads();
  const int lane = tid & 63;
  const int row = blockIdx.x * 4 + (tid >> 6);   // 0..511, guard <450
  if (row < 450) {
    const float2* Wr = (const float2*)(W + row * 450);  // 225 float2, 8B-aligned
    float acc = 0.f;
#pragma unroll
    for (int k = 0; k < 4; ++k) {
      int idx = lane + (k << 6);
      if (idx < 225) {
        float2 w = Wr[idx];
        acc += w.x * sv[2 * idx] + w.y * sv[2 * idx + 1];
      }
    }
#pragma unroll
    for (int off = 32; off > 0; off >>= 1) acc += __shfl_down(acc, off);
    if (lane == 0) {
      float r = acc + b[row];
      if (relu) r = fmaxf(r, 0.f);
      vout[row] = r;
    }
  }
}

// Fused K1..K5: f -> feat0 -> h1 -> feat -> h2, with 4 grid barriers.
__global__ __launch_bounds__(256) void k_front(
    const float* __restrict__ x, const float* __restrict__ TwE,
    const float* __restrict__ PE, const float* __restrict__ CE,
    const float* __restrict__ mE,
    const float* __restrict__ eW1, const float* __restrict__ eb1,
    const float* __restrict__ eW2, const float* __restrict__ eb2,
    const float* __restrict__ dW1, const float* __restrict__ db1,
    float* __restrict__ ws, int* __restrict__ cnt) {
  __shared__ float smem[1416];   // coef[1024] | sCE[128] | sPE[256] | sTw[4] | red[4]
  float* f     = ws + WS_F;
  float* feat0 = ws + WS_FEAT0;
  float* h1    = ws + WS_H1;
  float* feat  = ws + WS_FEAT;
  float* h2    = ws + WS_H2;
  const int tid = threadIdx.x;
  const int lane = tid & 63;

  // ---- Phase 0: f[i], i = blockIdx.x (grid = 128) ----
  {
    float* coef = smem;
    float* sCE  = smem + 1024;
    float* sPE  = smem + 1152;
    float* sTw  = smem + 1408;
    float* red  = smem + 1412;
    const int i = blockIdx.x;
    if (tid < 128) sCE[tid] = CE[tid * 128 + i];
    sPE[tid] = PE[tid * 128 + i];
    if (tid < 4) sTw[tid] = TwE[tid * 128 + i];
    __syncthreads();
#pragma unroll
    for (int k = 0; k < 4; ++k) {
      int q = tid + (k << 8);
      coef[q] = sTw[q >> 8] * sPE[q & 255];
    }
    __syncthreads();
    const int wv = tid >> 6;
    const float2 ce = ((const float2*)sCE)[lane];
    const float2* Xw = (const float2*)(x + 4 * 256 * 128);
    float acc = 0.f;
    const int q0 = wv * 256;
#pragma unroll 8
    for (int k = 0; k < 256; ++k) {
      int q = q0 + k;
      float2 v = Xw[q * 64 + lane];
      acc += coef[q] * (v.x * ce.x + v.y * ce.y);
    }
#pragma unroll
    for (int off = 32; off > 0; off >>= 1) acc += __shfl_down(acc, off);
    if (lane == 0) red[wv] = acc;
    __syncthreads();
    if (tid == 0) f[i] = red[0] + red[1] + red[2] + red[3];
  }
  gbar(cnt, 128);

  // ---- Phase 1: feat0 = mE @ f (450 rows, dot 128) ----
  {
    if (tid < 128) smem[tid] = f[tid];
    __syncthreads();
    const int row = blockIdx.x * 4 + (tid >> 6);
    if (row < 450) {
      float2 v = ((const float2*)(mE + row * 128))[lane];
      float acc = v.x * smem[2 * lane] + v.y * smem[2 * lane + 1];
#pragma unroll
      for (int off = 32; off > 0; off >>= 1) acc += __shfl_down(acc, off);
      if (lane == 0) feat0[row] = acc;
    }
  }
  gbar(cnt, 256);

  // ---- Phase 2: h1 = relu(eW1@feat0 + eb1) ----
  phase_mv450(eW1, eb1, feat0, h1, 1, smem);
  gbar(cnt, 384);

  // ---- Phase 3: feat = eW2@h1 + eb2 ----
  phase_mv450(eW2, eb2, h1, feat, 0, smem);
  gbar(cnt, 512);

  // ---- Phase 4: h2 = relu(dW1@feat + db1) ----
  phase_mv450(dW1, db1, feat, h2, 1, smem);
}

// K6: out = dec_W2 @ h2 + dec_b2. Wave per row, 4 rows per 256-thread block.
// Pure 236 MB HBM stream; nontemporal on W (read-once) and out (write-once).
__global__ __launch_bounds__(256) void k_dec2(
    const float* __restrict__ W, const float* __restrict__ b,
    const float* __restrict__ h, float* __restrict__ out) {
  __shared__ float sv[450];
  const int tid = threadIdx.x;
  if (tid < 450) sv[tid] = h[tid];
  if (tid + 256 < 450) sv[tid + 256] = h[tid + 256];
  __syncthreads();
  const int lane = tid & 63;
  const int row = blockIdx.x * 4 + (tid >> 6);  // exactly 131072 rows
  const vf2* Wr = (const vf2*)(W + (size_t)row * 450);
  float acc = 0.f;
#pragma unroll
  for (int k = 0; k < 4; ++k) {
    int idx = lane + (k << 6);
    if (idx < 225) {
      vf2 w = __builtin_nontemporal_load(&Wr[idx]);  // stream-once, skip L2 keep
      acc += w.x * sv[2 * idx] + w.y * sv[2 * idx + 1];
    }
  }
#pragma unroll
  for (int off = 32; off > 0; off >>= 1) acc += __shfl_down(acc, off);
  if (lane == 0) {
    float r = acc + b[row];
    __builtin_nontemporal_store(r, &out[row]);
  }
}

extern "C" void kernel_launch(void* const* d_in, const int* in_sizes, int n_in,
                              void* d_out, int out_size, void* d_ws, size_t ws_size,
                              hipStream_t stream) {
  const float* x   = (const float*)d_in[0];
  const float* TwE = (const float*)d_in[2];
  const float* PE  = (const float*)d_in[3];
  const float* CE  = (const float*)d_in[4];
  const float* mE  = (const float*)d_in[5];
  const float* eW1 = (const float*)d_in[6];
  const float* eb1 = (const float*)d_in[7];
  const float* eW2 = (const float*)d_in[8];
  const float* eb2 = (const float*)d_in[9];
  const float* dW1 = (const float*)d_in[10];
  const float* db1 = (const float*)d_in[11];
  const float* dW2 = (const float*)d_in[12];
  const float* db2 = (const float*)d_in[13];
  float* out = (float*)d_out;
  float* ws  = (float*)d_ws;
  int* cnt   = (int*)(ws + WS_CNT);

  (void)hipMemsetAsync((void*)cnt, 0, sizeof(int), stream);  // zero barrier counter
  k_front<<<128,   256, 0, stream>>>(x, TwE, PE, CE, mE, eW1, eb1, eW2, eb2,
                                     dW1, db1, ws, cnt);
  k_dec2 <<<32768, 256, 0, stream>>>(dW2, db2, ws + WS_H2, out);
}

// Round 5
// 374.725 us; speedup vs baseline: 1.0811x; 1.0811x over previous
//
#include <hip/hip_runtime.h>

// Native clang vector type — accepted by __builtin_nontemporal_load
typedef float vf4 __attribute__((ext_vector_type(4)));

// Workspace float offsets
#define WS_F     0      // f[128]
#define WS_FEAT0 128    // feat0[450]
#define WS_H1    640    // h1[450]
#define WS_FEAT  1152   // feat[450]
#define WS_H2    1664   // h2[450]

// K1: f[i] = sum_{t,p,c} x[4+t,p,c] * TwE[t,i] * PE[p,i] * CE[c,i]
// One block per i (128 blocks). Lanes split the contiguous c-dimension
// (float2 per lane), rows (t,p) iterate -> fully coalesced 512B wave loads.
__global__ __launch_bounds__(256) void k_f(
    const float* __restrict__ x, const float* __restrict__ TwE,
    const float* __restrict__ PE, const float* __restrict__ CE,
    float* __restrict__ f) {
  const int i = blockIdx.x;
  const int tid = threadIdx.x;
  __shared__ float sCE[128];
  __shared__ float sPE[256];
  __shared__ float sTw[4];
  __shared__ float coef[1024];
  __shared__ float red[4];
  if (tid < 128) sCE[tid] = CE[tid * 128 + i];
  sPE[tid] = PE[tid * 128 + i];
  if (tid < 4) sTw[tid] = TwE[tid * 128 + i];
  __syncthreads();
#pragma unroll
  for (int k = 0; k < 4; ++k) {
    int q = tid + (k << 8);
    coef[q] = sTw[q >> 8] * sPE[q & 255];
  }
  __syncthreads();
  const int lane = tid & 63;
  const int wv = tid >> 6;
  const float2 ce = ((const float2*)sCE)[lane];
  const float2* Xw = (const float2*)(x + 4 * 256 * 128);
  float acc = 0.f;
  const int q0 = wv * 256;
#pragma unroll 8
  for (int k = 0; k < 256; ++k) {
    int q = q0 + k;
    float2 v = Xw[q * 64 + lane];
    acc += coef[q] * (v.x * ce.x + v.y * ce.y);
  }
#pragma unroll
  for (int off = 32; off > 0; off >>= 1) acc += __shfl_down(acc, off);
  if (lane == 0) red[wv] = acc;
  __syncthreads();
  if (tid == 0) f[i] = red[0] + red[1] + red[2] + red[3];
}

// K2: feat0 = mE @ f  (450 rows, dot length 128). Wave per row.
__global__ __launch_bounds__(256) void k_mE(
    const float* __restrict__ mE, const float* __restrict__ f,
    float* __restrict__ feat0) {
  __shared__ float sf[128];
  const int tid = threadIdx.x;
  if (tid < 128) sf[tid] = f[tid];
  __syncthreads();
  const int lane = tid & 63;
  const int row = blockIdx.x * 4 + (tid >> 6);
  if (row >= 450) return;
  float2 v = ((const float2*)(mE + row * 128))[lane];
  float acc = v.x * sf[2 * lane] + v.y * sf[2 * lane + 1];
#pragma unroll
  for (int off = 32; off > 0; off >>= 1) acc += __shfl_down(acc, off);
  if (lane == 0) feat0[row] = acc;
}

// K3/K4/K5: vout = [relu](W @ vin + b), W is 450x450. Wave per row.
__global__ __launch_bounds__(256) void k_mv450(
    const float* __restrict__ W, const float* __restrict__ b,
    const float* __restrict__ vin, float* __restrict__ vout, int relu) {
  __shared__ float sv[450];
  const int tid = threadIdx.x;
  if (tid < 450) sv[tid] = vin[tid];
  if (tid + 256 < 450) sv[tid + 256] = vin[tid + 256];
  __syncthreads();
  const int lane = tid & 63;
  const int row = blockIdx.x * 4 + (tid >> 6);
  if (row >= 450) return;
  const float2* Wr = (const float2*)(W + row * 450);
  float acc = 0.f;
#pragma unroll
  for (int k = 0; k < 4; ++k) {
    int idx = lane + (k << 6);
    if (idx < 225) {
      float2 w = Wr[idx];
      acc += w.x * sv[2 * idx] + w.y * sv[2 * idx + 1];
    }
  }
#pragma unroll
  for (int off = 32; off > 0; off >>= 1) acc += __shfl_down(acc, off);
  if (lane == 0) {
    float r = acc + b[row];
    if (relu) r = fmaxf(r, 0.f);
    vout[row] = r;
  }
}

// K6: out = dec_W2 @ h2 + dec_b2. Wave per ROW-PAIR (900 floats = 225 float4,
// 16B-aligned: pair stride = 3600B). Nontemporal: W read once, out written once.
// Structure correctness-proven in R2's passing run.
__global__ __launch_bounds__(256) void k_dec2(
    const float* __restrict__ W, const float* __restrict__ b,
    const float* __restrict__ h, float* __restrict__ out) {
  __shared__ float sv2[900];
  const int tid = threadIdx.x;
  for (int k = tid; k < 900; k += 256) sv2[k] = h[k < 450 ? k : k - 450];
  __syncthreads();
  const int lane = tid & 63;
  const int rp = blockIdx.x * 4 + (tid >> 6);    // row pair, 0..65535
  const vf4* Wp = (const vf4*)(W + (size_t)rp * 900);
  float accA = 0.f, accB = 0.f;
#pragma unroll
  for (int k = 0; k < 3; ++k) {
    int j = lane + (k << 6);          // 0..191
    vf4 w = __builtin_nontemporal_load(&Wp[j]);
    const float* s = &sv2[4 * j];
    float p01 = w.x * s[0] + w.y * s[1];
    float p23 = w.z * s[2] + w.w * s[3];
    if (4 * j + 3 < 450)      accA += p01 + p23;   // j <= 111
    else if (4 * j >= 450)    accB += p01 + p23;   // j >= 113
    else { accA += p01; accB += p23; }             // j == 112 straddles
  }
  if (lane < 33) {                    // j = 192..224, all row B
    int j = 192 + lane;
    vf4 w = __builtin_nontemporal_load(&Wp[j]);
    const float* s = &sv2[4 * j];
    accB += w.x * s[0] + w.y * s[1] + w.z * s[2] + w.w * s[3];
  }
#pragma unroll
  for (int off = 32; off > 0; off >>= 1) {
    accA += __shfl_down(accA, off);
    accB += __shfl_down(accB, off);
  }
  if (lane == 0) {
    int r = rp * 2;
    __builtin_nontemporal_store(accA + b[r],     &out[r]);
    __builtin_nontemporal_store(accB + b[r + 1], &out[r + 1]);
  }
}

extern "C" void kernel_launch(void* const* d_in, const int* in_sizes, int n_in,
                              void* d_out, int out_size, void* d_ws, size_t ws_size,
                              hipStream_t stream) {
  const float* x   = (const float*)d_in[0];
  const float* TwE = (const float*)d_in[2];
  const float* PE  = (const float*)d_in[3];
  const float* CE  = (const float*)d_in[4];
  const float* mE  = (const float*)d_in[5];
  const float* eW1 = (const float*)d_in[6];
  const float* eb1 = (const float*)d_in[7];
  const float* eW2 = (const float*)d_in[8];
  const float* eb2 = (const float*)d_in[9];
  const float* dW1 = (const float*)d_in[10];
  const float* db1 = (const float*)d_in[11];
  const float* dW2 = (const float*)d_in[12];
  const float* db2 = (const float*)d_in[13];
  float* out = (float*)d_out;
  float* ws  = (float*)d_ws;

  k_f    <<<128,   256, 0, stream>>>(x, TwE, PE, CE, ws + WS_F);
  k_mE   <<<113,   256, 0, stream>>>(mE, ws + WS_F, ws + WS_FEAT0);
  k_mv450<<<113,   256, 0, stream>>>(eW1, eb1, ws + WS_FEAT0, ws + WS_H1, 1);
  k_mv450<<<113,   256, 0, stream>>>(eW2, eb2, ws + WS_H1, ws + WS_FEAT, 0);
  k_mv450<<<113,   256, 0, stream>>>(dW1, db1, ws + WS_FEAT, ws + WS_H2, 1);
  k_dec2 <<<16384, 256, 0, stream>>>(dW2, db2, ws + WS_H2, out);
}

// Round 6
// 367.904 us; speedup vs baseline: 1.1011x; 1.0185x over previous
//
#include <hip/hip_runtime.h>

// Native clang vector type — accepted by __builtin_nontemporal_load
typedef float vf4 __attribute__((ext_vector_type(4)));

// Workspace float offsets
#define WS_FPART 0      // fpart[2][128] (k_f partials; summed in k_h1)
#define WS_H1    640    // h1[450]
#define WS_FEAT  1152   // feat[450]
#define WS_H2    1664   // h2[450]

// K1: fpart[sub][i] = sum over half the (t,p) rows of x[4+t,p,c]*TwE[t,i]*PE[p,i]*CE[c,i]
// 256 blocks = 2 per output i (sub = t-half). Halves per-block L2-serial read vs R5.
__global__ __launch_bounds__(256) void k_f(
    const float* __restrict__ x, const float* __restrict__ TwE,
    const float* __restrict__ PE, const float* __restrict__ CE,
    float* __restrict__ fpart) {
  const int i   = blockIdx.x >> 1;
  const int sub = blockIdx.x & 1;          // 0: t=0,1  1: t=2,3
  const int tid = threadIdx.x;
  __shared__ float sCE[128];
  __shared__ float sPE[256];
  __shared__ float sTw[2];
  __shared__ float coef[512];
  __shared__ float red[4];
  if (tid < 128) sCE[tid] = CE[tid * 128 + i];
  sPE[tid] = PE[tid * 128 + i];
  if (tid < 2) sTw[tid] = TwE[(sub * 2 + tid) * 128 + i];
  __syncthreads();
#pragma unroll
  for (int k = 0; k < 2; ++k) {            // coef[l], l = local q = t_loc*256+p
    int l = tid + (k << 8);
    coef[l] = sTw[l >> 8] * sPE[l & 255];
  }
  __syncthreads();
  const int lane = tid & 63;
  const int wv = tid >> 6;
  const float2 ce = ((const float2*)sCE)[lane];
  const float2* Xw = (const float2*)(x + 4 * 256 * 128);  // window start
  float acc = 0.f;
  const int l0 = wv * 128;                 // each wave: 128 of this block's 512 rows
#pragma unroll 8
  for (int k = 0; k < 128; ++k) {
    int l = l0 + k;
    int q = (sub << 9) + l;                // global (t,p) row
    float2 v = Xw[q * 64 + lane];          // coalesced 512B wave load
    acc += coef[l] * (v.x * ce.x + v.y * ce.y);
  }
#pragma unroll
  for (int off = 32; off > 0; off >>= 1) acc += __shfl_down(acc, off);
  if (lane == 0) red[wv] = acc;
  __syncthreads();
  if (tid == 0) fpart[sub * 128 + i] = red[0] + red[1] + red[2] + red[3];
}

// K2+K3 merged: each block sums fpart -> f, redundantly computes feat0 = mE@f
// (450 rows, thread-per-row, mE L2-resident: 230 KB/block), then its 4 rows of
// h1 = relu(eW1@feat0 + eb1) wave-per-row. Kills one launch + its node gap.
__global__ __launch_bounds__(256) void k_h1(
    const float* __restrict__ fpart, const float* __restrict__ mE,
    const float* __restrict__ eW1, const float* __restrict__ eb1,
    float* __restrict__ h1) {
  __shared__ float sf[128];
  __shared__ float sfeat0[450];
  const int tid = threadIdx.x;
  if (tid < 128) sf[tid] = fpart[tid] + fpart[128 + tid];
  __syncthreads();
  for (int r = tid; r < 450; r += 256) {
    const float4* row = (const float4*)(mE + r * 128);  // 512B row, 16B-aligned
    float a0 = 0.f, a1 = 0.f, a2 = 0.f, a3 = 0.f;
#pragma unroll 8
    for (int k = 0; k < 32; ++k) {
      float4 m = row[k];
      a0 += m.x * sf[4 * k];      // LDS same-address across lanes: broadcast
      a1 += m.y * sf[4 * k + 1];
      a2 += m.z * sf[4 * k + 2];
      a3 += m.w * sf[4 * k + 3];
    }
    sfeat0[r] = (a0 + a1) + (a2 + a3);
  }
  __syncthreads();
  const int lane = tid & 63;
  const int row = blockIdx.x * 4 + (tid >> 6);
  if (row < 450) {
    const float2* Wr = (const float2*)(eW1 + row * 450);
    float acc = 0.f;
#pragma unroll
    for (int k = 0; k < 4; ++k) {
      int idx = lane + (k << 6);
      if (idx < 225) {
        float2 w = Wr[idx];
        acc += w.x * sfeat0[2 * idx] + w.y * sfeat0[2 * idx + 1];
      }
    }
#pragma unroll
    for (int off = 32; off > 0; off >>= 1) acc += __shfl_down(acc, off);
    if (lane == 0) h1[row] = fmaxf(acc + eb1[row], 0.f);
  }
}

// K4/K5: vout = [relu](W @ vin + b), W is 450x450. Wave per row.
__global__ __launch_bounds__(256) void k_mv450(
    const float* __restrict__ W, const float* __restrict__ b,
    const float* __restrict__ vin, float* __restrict__ vout, int relu) {
  __shared__ float sv[450];
  const int tid = threadIdx.x;
  if (tid < 450) sv[tid] = vin[tid];
  if (tid + 256 < 450) sv[tid + 256] = vin[tid + 256];
  __syncthreads();
  const int lane = tid & 63;
  const int row = blockIdx.x * 4 + (tid >> 6);
  if (row >= 450) return;
  const float2* Wr = (const float2*)(W + row * 450);
  float acc = 0.f;
#pragma unroll
  for (int k = 0; k < 4; ++k) {
    int idx = lane + (k << 6);
    if (idx < 225) {
      float2 w = Wr[idx];
      acc += w.x * sv[2 * idx] + w.y * sv[2 * idx + 1];
    }
  }
#pragma unroll
  for (int off = 32; off > 0; off >>= 1) acc += __shfl_down(acc, off);
  if (lane == 0) {
    float r = acc + b[row];
    if (relu) r = fmaxf(r, 0.f);
    vout[row] = r;
  }
}

// K6: out = dec_W2 @ h2 + dec_b2. Wave per ROW-PAIR (225 float4, 16B-aligned:
// pair stride 3600B). NT loads/stores: pure once-streamed 236 MB. At HBM floor.
__global__ __launch_bounds__(256) void k_dec2(
    const float* __restrict__ W, const float* __restrict__ b,
    const float* __restrict__ h, float* __restrict__ out) {
  __shared__ float sv2[900];
  const int tid = threadIdx.x;
  for (int k = tid; k < 900; k += 256) sv2[k] = h[k < 450 ? k : k - 450];
  __syncthreads();
  const int lane = tid & 63;
  const int rp = blockIdx.x * 4 + (tid >> 6);    // row pair, 0..65535
  const vf4* Wp = (const vf4*)(W + (size_t)rp * 900);
  float accA = 0.f, accB = 0.f;
#pragma unroll
  for (int k = 0; k < 3; ++k) {
    int j = lane + (k << 6);          // 0..191
    vf4 w = __builtin_nontemporal_load(&Wp[j]);
    const float* s = &sv2[4 * j];
    float p01 = w.x * s[0] + w.y * s[1];
    float p23 = w.z * s[2] + w.w * s[3];
    if (4 * j + 3 < 450)      accA += p01 + p23;   // j <= 111
    else if (4 * j >= 450)    accB += p01 + p23;   // j >= 113
    else { accA += p01; accB += p23; }             // j == 112 straddles
  }
  if (lane < 33) {                    // j = 192..224, all row B
    int j = 192 + lane;
    vf4 w = __builtin_nontemporal_load(&Wp[j]);
    const float* s = &sv2[4 * j];
    accB += w.x * s[0] + w.y * s[1] + w.z * s[2] + w.w * s[3];
  }
#pragma unroll
  for (int off = 32; off > 0; off >>= 1) {
    accA += __shfl_down(accA, off);
    accB += __shfl_down(accB, off);
  }
  if (lane == 0) {
    int r = rp * 2;
    __builtin_nontemporal_store(accA + b[r],     &out[r]);
    __builtin_nontemporal_store(accB + b[r + 1], &out[r + 1]);
  }
}

extern "C" void kernel_launch(void* const* d_in, const int* in_sizes, int n_in,
                              void* d_out, int out_size, void* d_ws, size_t ws_size,
                              hipStream_t stream) {
  const float* x   = (const float*)d_in[0];
  const float* TwE = (const float*)d_in[2];
  const float* PE  = (const float*)d_in[3];
  const float* CE  = (const float*)d_in[4];
  const float* mE  = (const float*)d_in[5];
  const float* eW1 = (const float*)d_in[6];
  const float* eb1 = (const float*)d_in[7];
  const float* eW2 = (const float*)d_in[8];
  const float* eb2 = (const float*)d_in[9];
  const float* dW1 = (const float*)d_in[10];
  const float* db1 = (const float*)d_in[11];
  const float* dW2 = (const float*)d_in[12];
  const float* db2 = (const float*)d_in[13];
  float* out = (float*)d_out;
  float* ws  = (float*)d_ws;

  k_f    <<<256,   256, 0, stream>>>(x, TwE, PE, CE, ws + WS_FPART);
  k_h1   <<<113,   256, 0, stream>>>(ws + WS_FPART, mE, eW1, eb1, ws + WS_H1);
  k_mv450<<<113,   256, 0, stream>>>(eW2, eb2, ws + WS_H1, ws + WS_FEAT, 0);
  k_mv450<<<113,   256, 0, stream>>>(dW1, db1, ws + WS_FEAT, ws + WS_H2, 1);
  k_dec2 <<<16384, 256, 0, stream>>>(dW2, db2, ws + WS_H2, out);
}

// Round 7
// 357.804 us; speedup vs baseline: 1.1322x; 1.0282x over previous
//
#include <hip/hip_runtime.h>

// Native clang vector type — accepted by __builtin_nontemporal_load
typedef float vf4 __attribute__((ext_vector_type(4)));

// Workspace float offsets
#define WS_FPART 0      // fpart[4][128] (k_f partials, one per t; summed in k_h1)
#define WS_H1    640    // h1[450]
#define WS_FEAT  1152   // feat[450]
#define WS_H2    1664   // h2[450]

// K1: fpart[t][i] = sum_{p,c} x[4+t,p,c] * TwE[t,i] * PE[p,i] * CE[c,i]
// 512 blocks = 4 per output i (one per t). Per-block L2-serial read = 128 KB.
__global__ __launch_bounds__(256) void k_f(
    const float* __restrict__ x, const float* __restrict__ TwE,
    const float* __restrict__ PE, const float* __restrict__ CE,
    float* __restrict__ fpart) {
  const int i = blockIdx.x >> 2;
  const int t = blockIdx.x & 3;
  const int tid = threadIdx.x;
  __shared__ float sCE[128];
  __shared__ float coef[256];   // coef[p] = TwE[t,i] * PE[p,i]
  __shared__ float red[4];
  const float tw = TwE[t * 128 + i];     // wave-uniform scalar load
  if (tid < 128) sCE[tid] = CE[tid * 128 + i];
  coef[tid] = tw * PE[tid * 128 + i];
  __syncthreads();
  const int lane = tid & 63;
  const int wv = tid >> 6;
  const float2 ce = ((const float2*)sCE)[lane];
  const float2* Xw = (const float2*)(x + 4 * 256 * 128);  // window start
  float acc = 0.f;
  const int l0 = wv * 64;                // each wave: 64 of this block's 256 p-rows
#pragma unroll 8
  for (int k = 0; k < 64; ++k) {
    int l = l0 + k;                      // p index
    int q = (t << 8) + l;                // global (t,p) row in window
    float2 v = Xw[q * 64 + lane];        // coalesced 512B wave load
    acc += coef[l] * (v.x * ce.x + v.y * ce.y);
  }
#pragma unroll
  for (int off = 32; off > 0; off >>= 1) acc += __shfl_down(acc, off);
  if (lane == 0) red[wv] = acc;
  __syncthreads();
  if (tid == 0) fpart[t * 128 + i] = red[0] + red[1] + red[2] + red[3];
}

// K2+K3 merged: each block sums fpart -> f, redundantly computes feat0 = mE@f
// (thread-per-row, mE 230 KB/block through L1), then its 4 rows of
// h1 = relu(eW1@feat0 + eb1) wave-per-row.
__global__ __launch_bounds__(256) void k_h1(
    const float* __restrict__ fpart, const float* __restrict__ mE,
    const float* __restrict__ eW1, const float* __restrict__ eb1,
    float* __restrict__ h1) {
  __shared__ float sf[128];
  __shared__ float sfeat0[450];
  const int tid = threadIdx.x;
  if (tid < 128)
    sf[tid] = (fpart[tid] + fpart[128 + tid]) + (fpart[256 + tid] + fpart[384 + tid]);
  __syncthreads();
  for (int r = tid; r < 450; r += 256) {
    const float4* row = (const float4*)(mE + r * 128);  // 512B row, 16B-aligned
    float a0 = 0.f, a1 = 0.f, a2 = 0.f, a3 = 0.f;
#pragma unroll 8
    for (int k = 0; k < 32; ++k) {
      float4 m = row[k];
      a0 += m.x * sf[4 * k];      // LDS same-address across lanes: broadcast
      a1 += m.y * sf[4 * k + 1];
      a2 += m.z * sf[4 * k + 2];
      a3 += m.w * sf[4 * k + 3];
    }
    sfeat0[r] = (a0 + a1) + (a2 + a3);
  }
  __syncthreads();
  const int lane = tid & 63;
  const int row = blockIdx.x * 4 + (tid >> 6);
  if (row < 450) {
    const float2* Wr = (const float2*)(eW1 + row * 450);
    float acc = 0.f;
#pragma unroll
    for (int k = 0; k < 4; ++k) {
      int idx = lane + (k << 6);
      if (idx < 225) {
        float2 w = Wr[idx];
        acc += w.x * sfeat0[2 * idx] + w.y * sfeat0[2 * idx + 1];
      }
    }
#pragma unroll
    for (int off = 32; off > 0; off >>= 1) acc += __shfl_down(acc, off);
    if (lane == 0) h1[row] = fmaxf(acc + eb1[row], 0.f);
  }
}

// K4/K5: vout = [relu](W @ vin + b), W is 450x450. Wave per row.
__global__ __launch_bounds__(256) void k_mv450(
    const float* __restrict__ W, const float* __restrict__ b,
    const float* __restrict__ vin, float* __restrict__ vout, int relu) {
  __shared__ float sv[450];
  const int tid = threadIdx.x;
  if (tid < 450) sv[tid] = vin[tid];
  if (tid + 256 < 450) sv[tid + 256] = vin[tid + 256];
  __syncthreads();
  const int lane = tid & 63;
  const int row = blockIdx.x * 4 + (tid >> 6);
  if (row >= 450) return;
  const float2* Wr = (const float2*)(W + row * 450);
  float acc = 0.f;
#pragma unroll
  for (int k = 0; k < 4; ++k) {
    int idx = lane + (k << 6);
    if (idx < 225) {
      float2 w = Wr[idx];
      acc += w.x * sv[2 * idx] + w.y * sv[2 * idx + 1];
    }
  }
#pragma unroll
  for (int off = 32; off > 0; off >>= 1) acc += __shfl_down(acc, off);
  if (lane == 0) {
    float r = acc + b[row];
    if (relu) r = fmaxf(r, 0.f);
    vout[row] = r;
  }
}

// K6: out = dec_W2 @ h2 + dec_b2. Wave per ROW-PAIR (225 float4, 16B-aligned:
// pair stride 3600B). NT loads/stores (once-streamed 236 MB). 512-thread
// blocks (8 pairs/block) halve the CP block-dispatch ramp vs 16384 blocks.
__global__ __launch_bounds__(512) void k_dec2(
    const float* __restrict__ W, const float* __restrict__ b,
    const float* __restrict__ h, float* __restrict__ out) {
  __shared__ float sv2[900];
  const int tid = threadIdx.x;
  for (int k = tid; k < 900; k += 512) sv2[k] = h[k < 450 ? k : k - 450];
  __syncthreads();
  const int lane = tid & 63;
  const int rp = blockIdx.x * 8 + (tid >> 6);    // row pair, 0..65535
  const vf4* Wp = (const vf4*)(W + (size_t)rp * 900);
  float accA = 0.f, accB = 0.f;
#pragma unroll
  for (int k = 0; k < 3; ++k) {
    int j = lane + (k << 6);          // 0..191
    vf4 w = __builtin_nontemporal_load(&Wp[j]);
    const float* s = &sv2[4 * j];
    float p01 = w.x * s[0] + w.y * s[1];
    float p23 = w.z * s[2] + w.w * s[3];
    if (4 * j + 3 < 450)      accA += p01 + p23;   // j <= 111
    else if (4 * j >= 450)    accB += p01 + p23;   // j >= 113
    else { accA += p01; accB += p23; }             // j == 112 straddles
  }
  if (lane < 33) {                    // j = 192..224, all row B
    int j = 192 + lane;
    vf4 w = __builtin_nontemporal_load(&Wp[j]);
    const float* s = &sv2[4 * j];
    accB += w.x * s[0] + w.y * s[1] + w.z * s[2] + w.w * s[3];
  }
#pragma unroll
  for (int off = 32; off > 0; off >>= 1) {
    accA += __shfl_down(accA, off);
    accB += __shfl_down(accB, off);
  }
  if (lane == 0) {
    int r = rp * 2;
    __builtin_nontemporal_store(accA + b[r],     &out[r]);
    __builtin_nontemporal_store(accB + b[r + 1], &out[r + 1]);
  }
}

extern "C" void kernel_launch(void* const* d_in, const int* in_sizes, int n_in,
                              void* d_out, int out_size, void* d_ws, size_t ws_size,
                              hipStream_t stream) {
  const float* x   = (const float*)d_in[0];
  const float* TwE = (const float*)d_in[2];
  const float* PE  = (const float*)d_in[3];
  const float* CE  = (const float*)d_in[4];
  const float* mE  = (const float*)d_in[5];
  const float* eW1 = (const float*)d_in[6];
  const float* eb1 = (const float*)d_in[7];
  const float* eW2 = (const float*)d_in[8];
  const float* eb2 = (const float*)d_in[9];
  const float* dW1 = (const float*)d_in[10];
  const float* db1 = (const float*)d_in[11];
  const float* dW2 = (const float*)d_in[12];
  const float* db2 = (const float*)d_in[13];
  float* out = (float*)d_out;
  float* ws  = (float*)d_ws;

  k_f    <<<512,  256, 0, stream>>>(x, TwE, PE, CE, ws + WS_FPART);
  k_h1   <<<113,  256, 0, stream>>>(ws + WS_FPART, mE, eW1, eb1, ws + WS_H1);
  k_mv450<<<113,  256, 0, stream>>>(eW2, eb2, ws + WS_H1, ws + WS_FEAT, 0);
  k_mv450<<<113,  256, 0, stream>>>(dW1, db1, ws + WS_FEAT, ws + WS_H2, 1);
  k_dec2 <<<8192, 512, 0, stream>>>(dW2, db2, ws + WS_H2, out);
}